// Round 2
// baseline (479.504 us; speedup 1.0000x reference)
//
#include <hip/hip_runtime.h>
#include <hip/hip_bf16.h>

#define T 128
#define F 64
#define H1 32
#define G1 128   // 4*H1
#define H2 16
#define G2 64    // 4*H2

typedef __attribute__((ext_vector_type(8))) short bf16x8;
typedef __attribute__((ext_vector_type(4))) float f32x4;

#define MFMA __builtin_amdgcn_mfma_f32_16x16x32_bf16

// Native-rate activations: v_exp + v_rcp (1-ulp class), far below bf16 rounding.
__device__ __forceinline__ float sigmoidf_(float x) {
    return __builtin_amdgcn_rcpf(1.0f + __expf(-x));
}
__device__ __forceinline__ float tanhf_(float x) {
    return 1.0f - 2.0f * __builtin_amdgcn_rcpf(__expf(2.0f * x) + 1.0f);
}
__device__ __forceinline__ unsigned short f2bf(float f) {
    union { float f; unsigned u; } c; c.f = f;
    unsigned r = c.u + 0x7FFF + ((c.u >> 16) & 1);   // RTNE
    return (unsigned short)(r >> 16);
}
// LDS-only barrier: waits DS ops, does NOT drain vmcnt (global prefetches
// stay in flight across the per-step sync).
__device__ __forceinline__ void lds_barrier() {
    asm volatile("s_waitcnt lgkmcnt(0)" ::: "memory");
    __builtin_amdgcn_s_barrier();
}

// =============================================================================
// K0: x fp32 -> bf16 in A-fragment-packed layout. Packed slot for
// (sample m, k = ks*32 + q*8 + j) = ks*512 + (m + 16*q)*8 + j  -> the 8
// shorts for one (m,ks,q) are CONTIGUOUS, so no LDS transpose is needed:
// thread = (t, m, ks, q): 2x float4 load (row-contiguous across ks,q lanes),
// 8 converts, one 16 B store. No __syncthreads, pure streaming.
// =============================================================================
__global__ __launch_bounds__(256) void xcvt(
    const float* __restrict__ x,          // [B][T][64]
    unsigned short* __restrict__ xbf)
{
    const int g = blockIdx.x;
    const int t = blockIdx.y * 2 + (threadIdx.x >> 7);
    const int r = threadIdx.x & 127;
    const int m = r & 15, ks = (r >> 4) & 1, q = r >> 5;   // q in 0..3
    const float* src = x + ((size_t)(g * 16 + m) * T + t) * 64 + ks * 32 + q * 8;
    const float4 v0 = *(const float4*)src;
    const float4 v1 = *(const float4*)(src + 4);
    bf16x8 u;
    u[0] = (short)f2bf(v0.x); u[1] = (short)f2bf(v0.y);
    u[2] = (short)f2bf(v0.z); u[3] = (short)f2bf(v0.w);
    u[4] = (short)f2bf(v1.x); u[5] = (short)f2bf(v1.y);
    u[6] = (short)f2bf(v1.z); u[7] = (short)f2bf(v1.w);
    *(bf16x8*)(xbf + (size_t)(g * T + t) * 1024 + ks * 512 + (m + 16 * q) * 8) = u;
}

// =============================================================================
// K1: layer-1 recurrence, TWO same-direction groups per block (shared W/U/b).
// 256 blocks x 4 waves (gh, sh) -> 1 wave/SIMD; each wave interleaves two
// independent recurrences per barrier round (ILP replaces TLP; barriers
// halve per stream-step). xa built one step ahead as before.
// =============================================================================
__global__ __launch_bounds__(256, 1) void lstm1_fused(
    const unsigned short* __restrict__ xbf,
    const float* __restrict__ W1f, const float* __restrict__ b1f, const float* __restrict__ U1f,
    const float* __restrict__ W1b, const float* __restrict__ b1b, const float* __restrict__ U1b,
    unsigned short* __restrict__ h1, const int ng)
{
    __shared__ unsigned short hb[2][2][640];   // [stream][buf][16*40]
    const int tid  = threadIdx.x;
    const int lane = tid & 63;
    const int wv   = __builtin_amdgcn_readfirstlane(tid >> 6);
    const int gh   = wv & 1;
    const int sh   = wv >> 1;            // 0..1
    const int n15  = lane & 15, quad = lane >> 4;
    const int d    = blockIdx.x & 1, gp = blockIdx.x >> 1;
    const int g0   = gp * 2;
    const int g1   = (g0 + 1 < ng) ? (g0 + 1) : g0;   // odd tail: benign dup

    const float* W  = d ? W1b : W1f;
    const float* U  = d ? U1b : U1f;
    const float* bs = d ? b1b : b1f;

    // frag q = 2*i + gh covers gate cols q*16+n15
    bf16x8 Wf[4][2], Uf[4];
    f32x4 biasC[4];
    #pragma unroll
    for (int i = 0; i < 4; ++i) {
        const int col = (2 * i + gh) * 16 + n15;
        biasC[i] = (f32x4)(bs[col]);
        #pragma unroll
        for (int ks = 0; ks < 2; ++ks) {
            bf16x8 f;
            #pragma unroll
            for (int j = 0; j < 8; ++j)
                f[j] = (short)f2bf(W[(ks * 32 + quad * 8 + j) * G1 + col]);
            Wf[i][ks] = f;
        }
        bf16x8 u;
        #pragma unroll
        for (int j = 0; j < 8; ++j)
            u[j] = (short)f2bf(U[(quad * 8 + j) * G1 + col]);
        Uf[i] = u;
    }

    // zero h(-1) buffers, both streams (2560 shorts)
    #pragma unroll
    for (int i = 0; i < 10; ++i) ((unsigned short*)hb)[tid + i * 256] = 0;

    float c0[2] = {0.f, 0.f}, c1[2] = {0.f, 0.f};
    const unsigned short* xb[2];
    unsigned short* hw[2];
    xb[0] = xbf + (size_t)g0 * T * 1024 + lane * 8;
    xb[1] = xbf + (size_t)g1 * T * 1024 + lane * 8;
    const int hoff = d * 512
        + ((quad * 4 + 2 * sh) + 16 * (gh * 2 + (n15 >> 3))) * 8 + (n15 & 7);
    hw[0] = h1 + (size_t)g0 * T * 1024 + hoff;
    hw[1] = h1 + (size_t)g1 * T * 1024 + hoff;

    // prologue: xa for step 0; prefetch x for step 1
    f32x4 xa[2][4];
    bf16x8 xP0[2], xP1[2];
    #pragma unroll
    for (int S = 0; S < 2; ++S) {
        const unsigned short* p0 = xb[S] + (size_t)(d ? (T - 1) : 0) * 1024;
        const bf16x8 t0 = *(const bf16x8*)p0, t1 = *(const bf16x8*)(p0 + 512);
        #pragma unroll
        for (int i = 0; i < 4; ++i) {
            xa[S][i] = MFMA(t0, Wf[i][0], biasC[i], 0, 0, 0);
            xa[S][i] = MFMA(t1, Wf[i][1], xa[S][i], 0, 0, 0);
        }
        const unsigned short* p1 = xb[S] + (size_t)(d ? (T - 2) : 1) * 1024;
        xP0[S] = *(const bf16x8*)p1;
        xP1[S] = *(const bf16x8*)(p1 + 512);
    }
    lds_barrier();

    #pragma unroll 1
    for (int s = 0; s < T; ++s) {
        const int t = d ? (T - 1 - s) : s;
        f32x4 a[2][4];
        // phase 1: recurrent U-MFMAs, both streams
        #pragma unroll
        for (int S = 0; S < 2; ++S) {
            const bf16x8 af = *(const bf16x8*)(hb[S][s & 1] + n15 * 40 + quad * 8);
            #pragma unroll
            for (int i = 0; i < 4; ++i)
                a[S][i] = MFMA(af, Uf[i], xa[S][i], 0, 0, 0);
        }
        // phase 2: xa rebuild for s+1 + prefetch x(s+2), both streams
        #pragma unroll
        for (int S = 0; S < 2; ++S) {
            #pragma unroll
            for (int i = 0; i < 4; ++i)
                xa[S][i] = MFMA(xP0[S], Wf[i][0], biasC[i], 0, 0, 0);
            #pragma unroll
            for (int i = 0; i < 4; ++i)
                xa[S][i] = MFMA(xP1[S], Wf[i][1], xa[S][i], 0, 0, 0);
            if (s + 2 < T) {
                const unsigned short* pn =
                    xb[S] + (size_t)(d ? (T - 3 - s) : (s + 2)) * 1024;
                xP0[S] = *(const bf16x8*)pn;
                xP1[S] = *(const bf16x8*)(pn + 512);
            }
        }
        // phase 3: activations + h writes, both streams
        #pragma unroll
        for (int S = 0; S < 2; ++S) {
            float zi0, zi1, zf0, zf1, zg0, zg1, zo0, zo1;
            if (sh == 0) {
                zi0 = a[S][0][0]; zi1 = a[S][0][1]; zf0 = a[S][1][0]; zf1 = a[S][1][1];
                zg0 = a[S][2][0]; zg1 = a[S][2][1]; zo0 = a[S][3][0]; zo1 = a[S][3][1];
            } else {
                zi0 = a[S][0][2]; zi1 = a[S][0][3]; zf0 = a[S][1][2]; zf1 = a[S][1][3];
                zg0 = a[S][2][2]; zg1 = a[S][2][3]; zo0 = a[S][3][2]; zo1 = a[S][3][3];
            }
            {   // sample quad*4 + 2*sh
                const float ig = sigmoidf_(zi0), fg = sigmoidf_(zf0);
                const float gg = tanhf_(zg0),   og = sigmoidf_(zo0);
                c0[S] = fg * c0[S] + ig * gg;
                const float h = og * tanhf_(c0[S]);
                const unsigned short us = f2bf(h);
                hb[S][(s + 1) & 1][(quad * 4 + 2 * sh) * 40 + gh * 16 + n15] = us;
                hw[S][(size_t)t * 1024] = us;
            }
            {   // sample quad*4 + 2*sh + 1
                const float ig = sigmoidf_(zi1), fg = sigmoidf_(zf1);
                const float gg = tanhf_(zg1),   og = sigmoidf_(zo1);
                c1[S] = fg * c1[S] + ig * gg;
                const float h = og * tanhf_(c1[S]);
                const unsigned short us = f2bf(h);
                hb[S][(s + 1) & 1][(quad * 4 + 2 * sh + 1) * 40 + gh * 16 + n15] = us;
                hw[S][(size_t)t * 1024 + 8] = us;
            }
        }
        lds_barrier();
    }
}

// =============================================================================
// K2: layer-2 recurrence, same stream pairing. 256 blocks x 4 waves (sh=0..3),
// two groups per block, both with direction d = blockIdx&1. h2_last -> hfin
// (fp32 [ns][32], d*16+col), head applied by K3.
// =============================================================================
__global__ __launch_bounds__(256, 1) void lstm2_rec(
    const unsigned short* __restrict__ h1,
    const float* __restrict__ W2f, const float* __restrict__ b2f, const float* __restrict__ U2f,
    const float* __restrict__ W2b, const float* __restrict__ b2b, const float* __restrict__ U2b,
    float* __restrict__ hfin, const int ng)
{
    __shared__ unsigned short hb2[2][2][400];   // [stream][buf], stride 24, padded
    const int tid  = threadIdx.x;
    const int lane = tid & 63;
    const int sh   = __builtin_amdgcn_readfirstlane(tid >> 6);   // 0..3
    const int n15  = lane & 15, quad = lane >> 4;
    const int d    = blockIdx.x & 1, gp = blockIdx.x >> 1;
    const int g0   = gp * 2;
    const int g1   = (g0 + 1 < ng) ? (g0 + 1) : g0;

    const float* W  = d ? W2b : W2f;
    const float* U  = d ? U2b : U2f;
    const float* bs = d ? b2b : b2f;

    bf16x8 Wf[4][2], Uf[4];
    f32x4 biasC[4];
    #pragma unroll
    for (int i = 0; i < 4; ++i) {
        const int col = i * 16 + n15;
        biasC[i] = (f32x4)(bs[col]);
        #pragma unroll
        for (int ks = 0; ks < 2; ++ks) {
            bf16x8 f;
            #pragma unroll
            for (int j = 0; j < 8; ++j)
                f[j] = (short)f2bf(W[(ks * 32 + quad * 8 + j) * G2 + col]);
            Wf[i][ks] = f;
        }
        bf16x8 u;
        #pragma unroll
        for (int j = 0; j < 8; ++j) {
            const int k = quad * 8 + j;
            u[j] = (k < H2) ? (short)f2bf(U[k * G2 + col]) : (short)0;
        }
        Uf[i] = u;
    }

    #pragma unroll
    for (int i = 0; i < 7; ++i) {
        const int idx = tid + i * 256;
        if (idx < 1600) ((unsigned short*)hb2)[idx] = 0;
    }

    float c[2] = {0.f, 0.f}, hlast[2] = {0.f, 0.f};
    const unsigned short* hl[2];
    hl[0] = h1 + (size_t)g0 * T * 1024 + lane * 8;
    hl[1] = h1 + (size_t)g1 * T * 1024 + lane * 8;

    f32x4 xa[2][4];
    bf16x8 xP0[2], xP1[2];
    #pragma unroll
    for (int S = 0; S < 2; ++S) {
        const unsigned short* p0 = hl[S] + (size_t)(d ? (T - 1) : 0) * 1024;
        const bf16x8 t0 = *(const bf16x8*)p0, t1 = *(const bf16x8*)(p0 + 512);
        #pragma unroll
        for (int i = 0; i < 4; ++i) {
            xa[S][i] = MFMA(t0, Wf[i][0], biasC[i], 0, 0, 0);
            xa[S][i] = MFMA(t1, Wf[i][1], xa[S][i], 0, 0, 0);
        }
        const unsigned short* p1 = hl[S] + (size_t)(d ? (T - 2) : 1) * 1024;
        xP0[S] = *(const bf16x8*)p1;
        xP1[S] = *(const bf16x8*)(p1 + 512);
    }
    lds_barrier();

    #pragma unroll 1
    for (int s = 0; s < T; ++s) {
        f32x4 a[2][4];
        #pragma unroll
        for (int S = 0; S < 2; ++S) {
            const bf16x8 af = *(const bf16x8*)(hb2[S][s & 1] + n15 * 24 + quad * 8);
            #pragma unroll
            for (int i = 0; i < 4; ++i)
                a[S][i] = MFMA(af, Uf[i], xa[S][i], 0, 0, 0);
        }
        #pragma unroll
        for (int S = 0; S < 2; ++S) {
            #pragma unroll
            for (int i = 0; i < 4; ++i)
                xa[S][i] = MFMA(xP0[S], Wf[i][0], biasC[i], 0, 0, 0);
            #pragma unroll
            for (int i = 0; i < 4; ++i)
                xa[S][i] = MFMA(xP1[S], Wf[i][1], xa[S][i], 0, 0, 0);
            if (s + 2 < T) {
                const unsigned short* pn =
                    hl[S] + (size_t)(d ? (T - 3 - s) : (s + 2)) * 1024;
                xP0[S] = *(const bf16x8*)pn;
                xP1[S] = *(const bf16x8*)(pn + 512);
            }
        }
        #pragma unroll
        for (int S = 0; S < 2; ++S) {
            float z0, z1, z2, z3;
            if (sh == 0)      { z0 = a[S][0][0]; z1 = a[S][1][0]; z2 = a[S][2][0]; z3 = a[S][3][0]; }
            else if (sh == 1) { z0 = a[S][0][1]; z1 = a[S][1][1]; z2 = a[S][2][1]; z3 = a[S][3][1]; }
            else if (sh == 2) { z0 = a[S][0][2]; z1 = a[S][1][2]; z2 = a[S][2][2]; z3 = a[S][3][2]; }
            else              { z0 = a[S][0][3]; z1 = a[S][1][3]; z2 = a[S][2][3]; z3 = a[S][3][3]; }
            const float ig = sigmoidf_(z0), fg = sigmoidf_(z1);
            const float gg = tanhf_(z2),   og = sigmoidf_(z3);
            c[S] = fg * c[S] + ig * gg;
            hlast[S] = og * tanhf_(c[S]);
            hb2[S][(s + 1) & 1][(quad * 4 + sh) * 24 + n15] = f2bf(hlast[S]);
        }
        lds_barrier();
    }

    hfin[((size_t)(g0 * 16 + quad * 4 + sh)) * 32 + d * 16 + n15] = hlast[0];
    hfin[((size_t)(g1 * 16 + quad * 4 + sh)) * 32 + d * 16 + n15] = hlast[1];
}

// =============================================================================
// K3: dense head. One thread per sample: [32] -> swish(W3) -> sigmoid(W4).
// =============================================================================
__global__ __launch_bounds__(256) void head(
    const float* __restrict__ hfin,
    const float* __restrict__ W3, const float* __restrict__ b3,
    const float* __restrict__ W4, const float* __restrict__ b4,
    float* __restrict__ out, const int ns)
{
    const int i = blockIdx.x * 256 + threadIdx.x;
    if (i >= ns) return;
    float h[32];
    #pragma unroll
    for (int k = 0; k < 8; ++k)
        *(float4*)(h + k * 4) = *(const float4*)(hfin + (size_t)i * 32 + k * 4);
    float y[8];
    #pragma unroll
    for (int u = 0; u < 8; ++u) {
        float a = b3[u];
        #pragma unroll
        for (int k = 0; k < 32; ++k) a += h[k] * W3[k * 8 + u];
        y[u] = a * sigmoidf_(a);
    }
    #pragma unroll
    for (int o = 0; o < 2; ++o) {
        float a = b4[o];
        #pragma unroll
        for (int u = 0; u < 8; ++u) a += y[u] * W4[u * 2 + o];
        out[(size_t)i * 2 + o] = sigmoidf_(a);
    }
}

extern "C" void kernel_launch(void* const* d_in, const int* in_sizes, int n_in,
                              void* d_out, int out_size, void* d_ws, size_t ws_size,
                              hipStream_t stream) {
    const float* x   = (const float*)d_in[0];
    const float* W1f = (const float*)d_in[1];
    const float* U1f = (const float*)d_in[2];
    const float* b1f = (const float*)d_in[3];
    const float* W1b = (const float*)d_in[4];
    const float* U1b = (const float*)d_in[5];
    const float* b1b = (const float*)d_in[6];
    const float* W2f = (const float*)d_in[7];
    const float* U2f = (const float*)d_in[8];
    const float* b2f = (const float*)d_in[9];
    const float* W2b = (const float*)d_in[10];
    const float* U2b = (const float*)d_in[11];
    const float* b2b = (const float*)d_in[12];
    const float* W3  = (const float*)d_in[13];
    const float* b3  = (const float*)d_in[14];
    const float* W4  = (const float*)d_in[15];
    const float* b4  = (const float*)d_in[16];
    float* out = (float*)d_out;

    const int B  = in_sizes[0] / (T * F);
    const int NG = B / 16;                       // sample groups

    // ws: xbf (256 KB/group) + h1 (256 KB/group); hfin (tiny, fp32) ALIASES
    // the xbf region — xbf is dead once lstm1 finishes, stream order is safe.
    const size_t perG = (size_t)T * 1024 * sizeof(unsigned short);  // 256 KB
    int chG = (int)(ws_size / (2 * perG));
    if (chG > NG) chG = NG;
    if (chG < 1) chG = 1;
    unsigned short* xbf = (unsigned short*)d_ws;
    unsigned short* h1  = xbf + (size_t)chG * T * 1024;

    for (int g0 = 0; g0 < NG; g0 += chG) {
        const int cg = (NG - g0 < chG) ? (NG - g0) : chG;
        dim3 gcv(cg, T / 2);
        xcvt<<<gcv, 256, 0, stream>>>(x + (size_t)g0 * 16 * T * F, xbf);
        const int np = (cg + 1) / 2;
        lstm1_fused<<<np * 2, 256, 0, stream>>>(
            xbf, W1f, b1f, U1f, W1b, b1b, U1b, h1, cg);
        lstm2_rec<<<np * 2, 256, 0, stream>>>(
            h1, W2f, b2f, U2f, W2b, b2b, U2b, (float*)xbf, cg);
        head<<<(cg * 16 + 255) / 256, 256, 0, stream>>>(
            (float*)xbf, W3, b3, W4, b4, out + (size_t)g0 * 16 * 2, cg * 16);
    }
}

// Round 3
// 423.921 us; speedup vs baseline: 1.1311x; 1.1311x over previous
//
#include <hip/hip_runtime.h>
#include <hip/hip_bf16.h>

#define T 128
#define F 64
#define H1 32
#define G1 128   // 4*H1
#define H2 16
#define G2 64    // 4*H2

typedef __attribute__((ext_vector_type(8))) short bf16x8;
typedef __attribute__((ext_vector_type(4))) float f32x4;

#define MFMA __builtin_amdgcn_mfma_f32_16x16x32_bf16

// Native-rate activations: v_exp + v_rcp (1-ulp class), far below bf16 rounding.
__device__ __forceinline__ float sigmoidf_(float x) {
    return __builtin_amdgcn_rcpf(1.0f + __expf(-x));
}
__device__ __forceinline__ float tanhf_(float x) {
    return 1.0f - 2.0f * __builtin_amdgcn_rcpf(__expf(2.0f * x) + 1.0f);
}
__device__ __forceinline__ unsigned short f2bf(float f) {
    union { float f; unsigned u; } c; c.f = f;
    unsigned r = c.u + 0x7FFF + ((c.u >> 16) & 1);   // RTNE
    return (unsigned short)(r >> 16);
}
// LDS-only barrier: waits DS ops, does NOT drain vmcnt.
__device__ __forceinline__ void lds_barrier() {
    asm volatile("s_waitcnt lgkmcnt(0)" ::: "memory");
    __builtin_amdgcn_s_barrier();
}

// =============================================================================
// K0: x fp32 -> bf16 in A-fragment-packed layout (syncless, LDS-free).
// Packed slot for (sample m, k = ks*32 + q*8 + j) = ks*512 + (m + 16*q)*8 + j.
// =============================================================================
__global__ __launch_bounds__(256) void xcvt(
    const float* __restrict__ x,          // [B][T][64]
    unsigned short* __restrict__ xbf)
{
    const int g = blockIdx.x;
    const int t = blockIdx.y * 2 + (threadIdx.x >> 7);
    const int r = threadIdx.x & 127;
    const int m = r & 15, ks = (r >> 4) & 1, q = r >> 5;   // q in 0..3
    const float* src = x + ((size_t)(g * 16 + m) * T + t) * 64 + ks * 32 + q * 8;
    const float4 v0 = *(const float4*)src;
    const float4 v1 = *(const float4*)(src + 4);
    bf16x8 u;
    u[0] = (short)f2bf(v0.x); u[1] = (short)f2bf(v0.y);
    u[2] = (short)f2bf(v0.z); u[3] = (short)f2bf(v0.w);
    u[4] = (short)f2bf(v1.x); u[5] = (short)f2bf(v1.y);
    u[6] = (short)f2bf(v1.z); u[7] = (short)f2bf(v1.w);
    *(bf16x8*)(xbf + (size_t)(g * T + t) * 1024 + ks * 512 + (m + 16 * q) * 8) = u;
}

// =============================================================================
// K1: layer-1 recurrence. Block = (g,d), 128 threads = 2 waves (gh = unit
// half). NO MFMA duplication: wave gh owns gate cols (2i+gh)*16+n15, i.e.
// gate i at unit gh*16+n15. C-layout row = quad*4+r -> each lane activates
// 4 samples x 1 unit (all four gates live in a[i][r], zero cross-lane).
// Per step: 12 MFMAs, 40 trans-instr, one 2-wave barrier. xa one step ahead.
// =============================================================================
__global__ __launch_bounds__(128) void lstm1(
    const unsigned short* __restrict__ xbf,
    const float* __restrict__ W1f, const float* __restrict__ b1f, const float* __restrict__ U1f,
    const float* __restrict__ W1b, const float* __restrict__ b1b, const float* __restrict__ U1b,
    unsigned short* __restrict__ h1)     // packed per (g,t), 1024 shorts
{
    __shared__ unsigned short hx[2][16 * 40];   // [buf][sample][unit], stride 40
    const int tid  = threadIdx.x;
    const int lane = tid & 63;
    const int gh   = __builtin_amdgcn_readfirstlane(tid >> 6);   // 0..1
    const int n15  = lane & 15, quad = lane >> 4;
    const int d    = blockIdx.x & 1, g = blockIdx.x >> 1;

    const float* W  = d ? W1b : W1f;
    const float* U  = d ? U1b : U1f;
    const float* bs = d ? b1b : b1f;

    // gate i, unit u = gh*16+n15  ->  col = i*32 + gh*16 + n15
    bf16x8 Wf[4][2], Uf[4];
    f32x4 biasC[4];
    #pragma unroll
    for (int i = 0; i < 4; ++i) {
        const int col = i * 32 + gh * 16 + n15;
        biasC[i] = (f32x4)(bs[col]);
        #pragma unroll
        for (int ks = 0; ks < 2; ++ks) {
            bf16x8 f;
            #pragma unroll
            for (int j = 0; j < 8; ++j)
                f[j] = (short)f2bf(W[(ks * 32 + quad * 8 + j) * G1 + col]);
            Wf[i][ks] = f;
        }
        bf16x8 uu;
        #pragma unroll
        for (int j = 0; j < 8; ++j)
            uu[j] = (short)f2bf(U[(quad * 8 + j) * G1 + col]);
        Uf[i] = uu;
    }

    // zero h(-1) buffers: 1280 shorts, 128 threads x 10
    #pragma unroll
    for (int i = 0; i < 10; ++i) ((unsigned short*)hx)[tid + i * 128] = 0;

    float c[4] = {0.f, 0.f, 0.f, 0.f};
    const unsigned short* xb = xbf + (size_t)g * T * 1024 + lane * 8;
    const int u = gh * 16 + n15;
    // h1 packed slot base for sample m=quad*4 (add r*8 per sample):
    // slot = d*512 + (m + 16*(u>>3))*8 + (u&7)
    unsigned short* hwp = h1 + (size_t)g * T * 1024 + d * 512
        + (quad * 4 + 16 * (gh * 2 + (n15 >> 3))) * 8 + (n15 & 7);

    // prologue: xa for step 0; prefetch x(1)
    f32x4 xa[4];
    bf16x8 xP0, xP1;
    {
        const unsigned short* p0 = xb + (size_t)(d ? (T - 1) : 0) * 1024;
        const bf16x8 t0 = *(const bf16x8*)p0, t1 = *(const bf16x8*)(p0 + 512);
        #pragma unroll
        for (int i = 0; i < 4; ++i) {
            xa[i] = MFMA(t0, Wf[i][0], biasC[i], 0, 0, 0);
            xa[i] = MFMA(t1, Wf[i][1], xa[i], 0, 0, 0);
        }
        const unsigned short* p1 = xb + (size_t)(d ? (T - 2) : 1) * 1024;
        xP0 = *(const bf16x8*)p1;
        xP1 = *(const bf16x8*)(p1 + 512);
    }
    lds_barrier();   // LDS zero + both waves ready

    #pragma unroll 1
    for (int s = 0; s < T; ++s) {
        // recurrent part: h(s-1) from LDS (both halves), one MFMA depth
        const bf16x8 af = *(const bf16x8*)(hx[s & 1] + n15 * 40 + quad * 8);
        f32x4 a0 = MFMA(af, Uf[0], xa[0], 0, 0, 0);
        f32x4 a1 = MFMA(af, Uf[1], xa[1], 0, 0, 0);
        f32x4 a2 = MFMA(af, Uf[2], xa[2], 0, 0, 0);
        f32x4 a3 = MFMA(af, Uf[3], xa[3], 0, 0, 0);

        // rebuild xa for s+1, prefetch x(s+2)
        #pragma unroll
        for (int i = 0; i < 4; ++i)
            xa[i] = MFMA(xP0, Wf[i][0], biasC[i], 0, 0, 0);
        #pragma unroll
        for (int i = 0; i < 4; ++i)
            xa[i] = MFMA(xP1, Wf[i][1], xa[i], 0, 0, 0);
        if (s + 2 < T) {
            const unsigned short* pn = xb + (size_t)(d ? (T - 3 - s) : (s + 2)) * 1024;
            xP0 = *(const bf16x8*)pn;
            xP1 = *(const bf16x8*)(pn + 512);
        }

        const int t = d ? (T - 1 - s) : s;
        unsigned short* hrow = hx[(s + 1) & 1];
        unsigned short* hg = hwp + (size_t)t * 1024;
        const f32x4 A0 = a0, A1 = a1, A2 = a2, A3 = a3;
        #pragma unroll
        for (int r = 0; r < 4; ++r) {
            const float ig = sigmoidf_(A0[r]);
            const float fg = sigmoidf_(A1[r]);
            const float gg = tanhf_(A2[r]);
            const float og = sigmoidf_(A3[r]);
            c[r] = fg * c[r] + ig * gg;
            const float h = og * tanhf_(c[r]);
            const unsigned short us = f2bf(h);
            hrow[(quad * 4 + r) * 40 + u] = us;
            hg[r * 8] = us;
        }
        lds_barrier();
    }
}

// =============================================================================
// K2: layer-2 recurrence, ONE wave per (g,d) stream — no barriers at all.
// Gate i at col i*16+n15 -> each lane activates 4 samples x unit n15 with
// all gates in-register. h-exchange is same-wave LDS write->read (in-order
// DS + lgkmcnt). U zero-padded to K=32 (af quads 2,3 read zeroed region).
// =============================================================================
__global__ __launch_bounds__(64) void lstm2(
    const unsigned short* __restrict__ h1,
    const float* __restrict__ W2f, const float* __restrict__ b2f, const float* __restrict__ U2f,
    const float* __restrict__ W2b, const float* __restrict__ b2b, const float* __restrict__ U2b,
    float* __restrict__ hfin)            // [ns][32]
{
    __shared__ unsigned short hx[2][16 * 40];   // zeroed; cols >=16 stay 0
    const int lane = threadIdx.x;
    const int n15  = lane & 15, quad = lane >> 4;
    const int d    = blockIdx.x & 1, g = blockIdx.x >> 1;

    const float* W  = d ? W2b : W2f;
    const float* U  = d ? U2b : U2f;
    const float* bs = d ? b2b : b2f;

    bf16x8 Wf[4][2], Uf[4];
    f32x4 biasC[4];
    #pragma unroll
    for (int i = 0; i < 4; ++i) {
        const int col = i * 16 + n15;        // gate i, unit n15
        biasC[i] = (f32x4)(bs[col]);
        #pragma unroll
        for (int ks = 0; ks < 2; ++ks) {
            bf16x8 f;
            #pragma unroll
            for (int j = 0; j < 8; ++j)
                f[j] = (short)f2bf(W[(ks * 32 + quad * 8 + j) * G2 + col]);
            Wf[i][ks] = f;
        }
        bf16x8 uu;
        #pragma unroll
        for (int j = 0; j < 8; ++j) {
            const int k = quad * 8 + j;
            uu[j] = (k < H2) ? (short)f2bf(U[k * G2 + col]) : (short)0;
        }
        Uf[i] = uu;
    }

    // zero both buffers: 1280 shorts / 64 lanes = 20 each
    #pragma unroll
    for (int i = 0; i < 20; ++i) ((unsigned short*)hx)[lane + i * 64] = 0;

    float c[4] = {0.f, 0.f, 0.f, 0.f};
    float hl4[4] = {0.f, 0.f, 0.f, 0.f};
    const unsigned short* hl = h1 + (size_t)g * T * 1024 + lane * 8;

    f32x4 xa[4];
    bf16x8 xP0, xP1;
    {
        const unsigned short* p0 = hl + (size_t)(d ? (T - 1) : 0) * 1024;
        const bf16x8 t0 = *(const bf16x8*)p0, t1 = *(const bf16x8*)(p0 + 512);
        #pragma unroll
        for (int i = 0; i < 4; ++i) {
            xa[i] = MFMA(t0, Wf[i][0], biasC[i], 0, 0, 0);
            xa[i] = MFMA(t1, Wf[i][1], xa[i], 0, 0, 0);
        }
        const unsigned short* p1 = hl + (size_t)(d ? (T - 2) : 1) * 1024;
        xP0 = *(const bf16x8*)p1;
        xP1 = *(const bf16x8*)(p1 + 512);
    }
    asm volatile("s_waitcnt lgkmcnt(0)" ::: "memory");   // LDS zero done (same wave)

    #pragma unroll 1
    for (int s = 0; s < T; ++s) {
        const bf16x8 af = *(const bf16x8*)(hx[s & 1] + n15 * 40 + quad * 8);
        f32x4 a0 = MFMA(af, Uf[0], xa[0], 0, 0, 0);
        f32x4 a1 = MFMA(af, Uf[1], xa[1], 0, 0, 0);
        f32x4 a2 = MFMA(af, Uf[2], xa[2], 0, 0, 0);
        f32x4 a3 = MFMA(af, Uf[3], xa[3], 0, 0, 0);

        #pragma unroll
        for (int i = 0; i < 4; ++i)
            xa[i] = MFMA(xP0, Wf[i][0], biasC[i], 0, 0, 0);
        #pragma unroll
        for (int i = 0; i < 4; ++i)
            xa[i] = MFMA(xP1, Wf[i][1], xa[i], 0, 0, 0);
        if (s + 2 < T) {
            const unsigned short* pn = hl + (size_t)(d ? (T - 3 - s) : (s + 2)) * 1024;
            xP0 = *(const bf16x8*)pn;
            xP1 = *(const bf16x8*)(pn + 512);
        }

        unsigned short* hrow = hx[(s + 1) & 1];
        #pragma unroll
        for (int r = 0; r < 4; ++r) {
            const float ig = sigmoidf_(a0[r]);
            const float fg = sigmoidf_(a1[r]);
            const float gg = tanhf_(a2[r]);
            const float og = sigmoidf_(a3[r]);
            c[r] = fg * c[r] + ig * gg;
            hl4[r] = og * tanhf_(c[r]);
            hrow[(quad * 4 + r) * 40 + n15] = f2bf(hl4[r]);
        }
        // same-wave DS in-order + compiler lgkmcnt: no barrier needed
    }

    #pragma unroll
    for (int r = 0; r < 4; ++r)
        hfin[(size_t)(g * 16 + quad * 4 + r) * 32 + d * 16 + n15] = hl4[r];
}

// =============================================================================
// K3: dense head. One thread per sample: [32] -> swish(W3) -> sigmoid(W4).
// =============================================================================
__global__ __launch_bounds__(256) void head(
    const float* __restrict__ hfin,
    const float* __restrict__ W3, const float* __restrict__ b3,
    const float* __restrict__ W4, const float* __restrict__ b4,
    float* __restrict__ out, const int ns)
{
    const int i = blockIdx.x * 256 + threadIdx.x;
    if (i >= ns) return;
    float h[32];
    #pragma unroll
    for (int k = 0; k < 8; ++k)
        *(float4*)(h + k * 4) = *(const float4*)(hfin + (size_t)i * 32 + k * 4);
    float y[8];
    #pragma unroll
    for (int u = 0; u < 8; ++u) {
        float a = b3[u];
        #pragma unroll
        for (int k = 0; k < 32; ++k) a += h[k] * W3[k * 8 + u];
        y[u] = a * sigmoidf_(a);
    }
    #pragma unroll
    for (int o = 0; o < 2; ++o) {
        float a = b4[o];
        #pragma unroll
        for (int u = 0; u < 8; ++u) a += y[u] * W4[u * 2 + o];
        out[(size_t)i * 2 + o] = sigmoidf_(a);
    }
}

extern "C" void kernel_launch(void* const* d_in, const int* in_sizes, int n_in,
                              void* d_out, int out_size, void* d_ws, size_t ws_size,
                              hipStream_t stream) {
    const float* x   = (const float*)d_in[0];
    const float* W1f = (const float*)d_in[1];
    const float* U1f = (const float*)d_in[2];
    const float* b1f = (const float*)d_in[3];
    const float* W1b = (const float*)d_in[4];
    const float* U1b = (const float*)d_in[5];
    const float* b1b = (const float*)d_in[6];
    const float* W2f = (const float*)d_in[7];
    const float* U2f = (const float*)d_in[8];
    const float* b2f = (const float*)d_in[9];
    const float* W2b = (const float*)d_in[10];
    const float* U2b = (const float*)d_in[11];
    const float* b2b = (const float*)d_in[12];
    const float* W3  = (const float*)d_in[13];
    const float* b3  = (const float*)d_in[14];
    const float* W4  = (const float*)d_in[15];
    const float* b4  = (const float*)d_in[16];
    float* out = (float*)d_out;

    const int B  = in_sizes[0] / (T * F);
    const int NG = B / 16;                       // sample groups

    // ws: xbf (256 KB/group) + h1 (256 KB/group); hfin (fp32, tiny) ALIASES
    // the xbf region — xbf is dead once lstm1 finishes; stream order is safe.
    const size_t perG = (size_t)T * 1024 * sizeof(unsigned short);  // 256 KB
    int chG = (int)(ws_size / (2 * perG));
    if (chG > NG) chG = NG;
    if (chG < 1) chG = 1;
    unsigned short* xbf = (unsigned short*)d_ws;
    unsigned short* h1  = xbf + (size_t)chG * T * 1024;

    for (int g0 = 0; g0 < NG; g0 += chG) {
        const int cg = (NG - g0 < chG) ? (NG - g0) : chG;
        dim3 gcv(cg, T / 2);
        xcvt<<<gcv, 256, 0, stream>>>(x + (size_t)g0 * 16 * T * F, xbf);
        lstm1<<<cg * 2, 128, 0, stream>>>(
            xbf, W1f, b1f, U1f, W1b, b1b, U1b, h1);
        lstm2<<<cg * 2, 64, 0, stream>>>(
            h1, W2f, b2f, U2f, W2b, b2b, U2b, (float*)xbf);
        head<<<(cg * 16 + 255) / 256, 256, 0, stream>>>(
            (float*)xbf, W3, b3, W4, b4, out + (size_t)g0 * 16 * 2, cg * 16);
    }
}

// Round 4
// 369.755 us; speedup vs baseline: 1.2968x; 1.1465x over previous
//
#include <hip/hip_runtime.h>
#include <hip/hip_bf16.h>

#define T 128
#define F 64
#define H1 32
#define G1 128   // 4*H1
#define H2 16
#define G2 64    // 4*H2

typedef __attribute__((ext_vector_type(8))) short bf16x8;
typedef __attribute__((ext_vector_type(4))) float f32x4;

#define MFMA __builtin_amdgcn_mfma_f32_16x16x32_bf16

// Native-rate activations: v_exp + v_rcp (1-ulp class), far below bf16 rounding.
__device__ __forceinline__ float sigmoidf_(float x) {
    return __builtin_amdgcn_rcpf(1.0f + __expf(-x));
}
__device__ __forceinline__ float tanhf_(float x) {
    return 1.0f - 2.0f * __builtin_amdgcn_rcpf(__expf(2.0f * x) + 1.0f);
}
__device__ __forceinline__ unsigned short f2bf(float f) {
    union { float f; unsigned u; } c; c.f = f;
    unsigned r = c.u + 0x7FFF + ((c.u >> 16) & 1);   // RTNE
    return (unsigned short)(r >> 16);
}
// LDS-only barrier: waits DS ops, does NOT drain vmcnt.
__device__ __forceinline__ void lds_barrier() {
    asm volatile("s_waitcnt lgkmcnt(0)" ::: "memory");
    __builtin_amdgcn_s_barrier();
}

// =============================================================================
// K0: x fp32 -> bf16, A-fragment-packed. COALESCED loads: thread = one
// float4 in memory order; store = 8 B to the packed slot (scattered within
// the (g,t) 2 KB region only). Syncless, LDS-free.
// slot(m, k) = (k>>5)*512 + (m + 16*((k&31)>>3))*8 + (k&7)
// =============================================================================
__global__ __launch_bounds__(256) void xcvt(
    const float* __restrict__ x,          // [B][T][64]
    unsigned short* __restrict__ xbf)
{
    const size_t fi = (size_t)blockIdx.x * 256 + threadIdx.x;  // float4 index
    const int c4 = (int)(fi & 15);            // float4 within row
    const size_t row = fi >> 4;               // (b, t)
    const int t = (int)(row & (T - 1));
    const size_t b = row >> 7;
    const int m = (int)(b & 15);
    const size_t g = b >> 4;

    const float4 v = *(const float4*)(x + fi * 4);
    ushort4 u;
    u.x = f2bf(v.x); u.y = f2bf(v.y); u.z = f2bf(v.z); u.w = f2bf(v.w);
    const int ks = c4 >> 3;
    const int q  = (c4 & 7) >> 1;
    const int j0 = (c4 & 1) * 4;
    *(ushort4*)(xbf + ((size_t)(g * T + t)) * 1024 + ks * 512 + (m + 16 * q) * 8 + j0) = u;
}

// =============================================================================
// K1: layer-1 recurrence (r1-proven shape, byte-identical logic).
// Block = (g, d), 4 waves (gh = gate-half, sh = sample-half); 2 blocks/CU,
// 2 waves/SIMD. xa = bias + x(t)W built one step ahead; post-barrier path is
// ds_read -> 1 U-MFMA -> activation.
// =============================================================================
__global__ __launch_bounds__(256, 2) void lstm1_fused(
    const unsigned short* __restrict__ xbf,
    const float* __restrict__ W1f, const float* __restrict__ b1f, const float* __restrict__ U1f,
    const float* __restrict__ W1b, const float* __restrict__ b1b, const float* __restrict__ U1b,
    unsigned short* __restrict__ h1)     // packed per (g,t), 1024 shorts
{
    __shared__ unsigned short hb[2][16 * 40];
    const int tid  = threadIdx.x;
    const int lane = tid & 63;
    const int wv   = __builtin_amdgcn_readfirstlane(tid >> 6);
    const int gh   = wv & 1;
    const int sh   = wv >> 1;            // 0..1
    const int n15  = lane & 15, quad = lane >> 4;
    const int d    = blockIdx.x & 1, g = blockIdx.x >> 1;

    const float* W  = d ? W1b : W1f;
    const float* U  = d ? U1b : U1f;
    const float* bs = d ? b1b : b1f;

    // frag q = 2*i + gh covers gate cols q*16+n15
    bf16x8 Wf[4][2], Uf[4];
    f32x4 biasC[4];
    #pragma unroll
    for (int i = 0; i < 4; ++i) {
        const int col = (2 * i + gh) * 16 + n15;
        biasC[i] = (f32x4)(bs[col]);
        #pragma unroll
        for (int ks = 0; ks < 2; ++ks) {
            bf16x8 f;
            #pragma unroll
            for (int j = 0; j < 8; ++j)
                f[j] = (short)f2bf(W[(ks * 32 + quad * 8 + j) * G1 + col]);
            Wf[i][ks] = f;
        }
        bf16x8 u;
        #pragma unroll
        for (int j = 0; j < 8; ++j)
            u[j] = (short)f2bf(U[(quad * 8 + j) * G1 + col]);
        Uf[i] = u;
    }

    // zero h(-1) buffer + pads (1280 shorts total)
    #pragma unroll
    for (int i = 0; i < 5; ++i) ((unsigned short*)hb)[tid + i * 256] = 0;

    float c0 = 0.0f, c1 = 0.0f;
    const unsigned short* xb = xbf + (size_t)g * T * 1024 + lane * 8;
    unsigned short* h1b0 = h1 + (size_t)g * T * 1024
        + d * 512 + ((quad * 4 + 2 * sh) + 16 * (gh * 2 + (n15 >> 3))) * 8 + (n15 & 7);
    unsigned short* h1b1 = h1b0 + 8;

    // prologue: xa for steps 0/1; prefetch x for steps 2/3
    f32x4 xaA[4], xaB[4];
    bf16x8 xA0, xA1, xB0, xB1;
    {
        const unsigned short* p0 = xb + (size_t)(d ? (T - 1) : 0) * 1024;
        bf16x8 t0 = *(const bf16x8*)(p0), t1 = *(const bf16x8*)(p0 + 512);
        #pragma unroll
        for (int i = 0; i < 4; ++i) {
            xaA[i] = MFMA(t0, Wf[i][0], biasC[i], 0, 0, 0);
            xaA[i] = MFMA(t1, Wf[i][1], xaA[i], 0, 0, 0);
        }
        const unsigned short* p1 = xb + (size_t)(d ? (T - 2) : 1) * 1024;
        t0 = *(const bf16x8*)(p1); t1 = *(const bf16x8*)(p1 + 512);
        #pragma unroll
        for (int i = 0; i < 4; ++i) {
            xaB[i] = MFMA(t0, Wf[i][0], biasC[i], 0, 0, 0);
            xaB[i] = MFMA(t1, Wf[i][1], xaB[i], 0, 0, 0);
        }
        const unsigned short* p2 = xb + (size_t)(d ? (T - 3) : 2) * 1024;
        xA0 = *(const bf16x8*)(p2); xA1 = *(const bf16x8*)(p2 + 512);
        const unsigned short* p3 = xb + (size_t)(d ? (T - 4) : 3) * 1024;
        xB0 = *(const bf16x8*)(p3); xB1 = *(const bf16x8*)(p3 + 512);
    }
    lds_barrier();

    auto step = [&](int s, f32x4* xa, bf16x8& x0, bf16x8& x1) {
        const bf16x8 af = *(const bf16x8*)(hb[s & 1] + n15 * 40 + quad * 8);
        f32x4 a0 = MFMA(af, Uf[0], xa[0], 0, 0, 0);
        f32x4 a1 = MFMA(af, Uf[1], xa[1], 0, 0, 0);
        f32x4 a2 = MFMA(af, Uf[2], xa[2], 0, 0, 0);
        f32x4 a3 = MFMA(af, Uf[3], xa[3], 0, 0, 0);

        xa[0] = MFMA(x0, Wf[0][0], biasC[0], 0, 0, 0);
        xa[1] = MFMA(x0, Wf[1][0], biasC[1], 0, 0, 0);
        xa[2] = MFMA(x0, Wf[2][0], biasC[2], 0, 0, 0);
        xa[3] = MFMA(x0, Wf[3][0], biasC[3], 0, 0, 0);
        xa[0] = MFMA(x1, Wf[0][1], xa[0], 0, 0, 0);
        xa[1] = MFMA(x1, Wf[1][1], xa[1], 0, 0, 0);
        xa[2] = MFMA(x1, Wf[2][1], xa[2], 0, 0, 0);
        xa[3] = MFMA(x1, Wf[3][1], xa[3], 0, 0, 0);

        if (s + 4 < T) {
            const unsigned short* pn = xb + (size_t)(d ? (T - 5 - s) : (s + 4)) * 1024;
            x0 = *(const bf16x8*)(pn); x1 = *(const bf16x8*)(pn + 512);
        }

        const int t = d ? (T - 1 - s) : s;
        float zi0, zi1, zf0, zf1, zg0, zg1, zo0, zo1;
        if (sh == 0) {
            zi0 = a0[0]; zi1 = a0[1]; zf0 = a1[0]; zf1 = a1[1];
            zg0 = a2[0]; zg1 = a2[1]; zo0 = a3[0]; zo1 = a3[1];
        } else {
            zi0 = a0[2]; zi1 = a0[3]; zf0 = a1[2]; zf1 = a1[3];
            zg0 = a2[2]; zg1 = a2[3]; zo0 = a3[2]; zo1 = a3[3];
        }
        {   // sample quad*4 + 2*sh
            const float ig = sigmoidf_(zi0), fg = sigmoidf_(zf0);
            const float gg = tanhf_(zg0),   og = sigmoidf_(zo0);
            c0 = fg * c0 + ig * gg;
            const float h = og * tanhf_(c0);
            const unsigned short us = f2bf(h);
            hb[(s + 1) & 1][(quad * 4 + 2 * sh) * 40 + gh * 16 + n15] = us;
            h1b0[(size_t)t * 1024] = us;
        }
        {   // sample quad*4 + 2*sh + 1
            const float ig = sigmoidf_(zi1), fg = sigmoidf_(zf1);
            const float gg = tanhf_(zg1),   og = sigmoidf_(zo1);
            c1 = fg * c1 + ig * gg;
            const float h = og * tanhf_(c1);
            const unsigned short us = f2bf(h);
            hb[(s + 1) & 1][(quad * 4 + 2 * sh + 1) * 40 + gh * 16 + n15] = us;
            h1b1[(size_t)t * 1024] = us;
        }
        lds_barrier();
    };

    #pragma unroll 1
    for (int s = 0; s < T; s += 2) {
        step(s, xaA, xA0, xA1);
        step(s + 1, xaB, xB0, xB1);
    }
}

// =============================================================================
// K2: layer-2 recurrence in the r1-lstm1 SHAPE: block = (g, d), 512 blocks
// x 4 waves (sh = 0..3) -> 2 blocks/CU, 2 waves/SIMD, 4-wave barrier.
// MFMAs duplicated across sh (cheap: 60 cyc/SIMD); activation is 1 elem/lane
// (full lane efficiency): wave sh activates sample quad*4+sh, unit n15,
// gates in a0..a3[sh]. U2 zero-padded to K=32 via zeroed LDS cols 16..39.
// =============================================================================
__global__ __launch_bounds__(256, 2) void lstm2_rec(
    const unsigned short* __restrict__ h1,
    const float* __restrict__ W2f, const float* __restrict__ b2f, const float* __restrict__ U2f,
    const float* __restrict__ W2b, const float* __restrict__ b2b, const float* __restrict__ U2b,
    float* __restrict__ hfin)            // [ns][32]
{
    __shared__ unsigned short hx[2][16 * 40];   // cols 16..39 stay zero
    const int tid  = threadIdx.x;
    const int lane = tid & 63;
    const int sh   = __builtin_amdgcn_readfirstlane(tid >> 6);   // 0..3
    const int n15  = lane & 15, quad = lane >> 4;
    const int d    = blockIdx.x & 1, g = blockIdx.x >> 1;

    const float* W  = d ? W2b : W2f;
    const float* U  = d ? U2b : U2f;
    const float* bs = d ? b2b : b2f;

    bf16x8 Wf[4][2], Uf[4];
    f32x4 biasC[4];
    #pragma unroll
    for (int i = 0; i < 4; ++i) {
        const int col = i * 16 + n15;        // gate i, unit n15
        biasC[i] = (f32x4)(bs[col]);
        #pragma unroll
        for (int ks = 0; ks < 2; ++ks) {
            bf16x8 f;
            #pragma unroll
            for (int j = 0; j < 8; ++j)
                f[j] = (short)f2bf(W[(ks * 32 + quad * 8 + j) * G2 + col]);
            Wf[i][ks] = f;
        }
        bf16x8 uu;
        #pragma unroll
        for (int j = 0; j < 8; ++j) {
            const int k = quad * 8 + j;
            uu[j] = (k < H2) ? (short)f2bf(U[k * G2 + col]) : (short)0;
        }
        Uf[i] = uu;
    }

    // zero both buffers: 1280 shorts / 256 threads = 5 each
    #pragma unroll
    for (int i = 0; i < 5; ++i) ((unsigned short*)hx)[tid + i * 256] = 0;

    float c = 0.0f, hlast = 0.0f;
    const unsigned short* hl = h1 + (size_t)g * T * 1024 + lane * 8;

    f32x4 xaA[4], xaB[4];
    bf16x8 hA0, hA1, hB0, hB1;
    {
        const unsigned short* p0 = hl + (size_t)(d ? (T - 1) : 0) * 1024;
        bf16x8 t0 = *(const bf16x8*)(p0), t1 = *(const bf16x8*)(p0 + 512);
        #pragma unroll
        for (int i = 0; i < 4; ++i) {
            xaA[i] = MFMA(t0, Wf[i][0], biasC[i], 0, 0, 0);
            xaA[i] = MFMA(t1, Wf[i][1], xaA[i], 0, 0, 0);
        }
        const unsigned short* p1 = hl + (size_t)(d ? (T - 2) : 1) * 1024;
        t0 = *(const bf16x8*)(p1); t1 = *(const bf16x8*)(p1 + 512);
        #pragma unroll
        for (int i = 0; i < 4; ++i) {
            xaB[i] = MFMA(t0, Wf[i][0], biasC[i], 0, 0, 0);
            xaB[i] = MFMA(t1, Wf[i][1], xaB[i], 0, 0, 0);
        }
        const unsigned short* p2 = hl + (size_t)(d ? (T - 3) : 2) * 1024;
        hA0 = *(const bf16x8*)(p2); hA1 = *(const bf16x8*)(p2 + 512);
        const unsigned short* p3 = hl + (size_t)(d ? (T - 4) : 3) * 1024;
        hB0 = *(const bf16x8*)(p3); hB1 = *(const bf16x8*)(p3 + 512);
    }
    lds_barrier();

    auto step = [&](int s, f32x4* xa, bf16x8& x0, bf16x8& x1) {
        const bf16x8 af = *(const bf16x8*)(hx[s & 1] + n15 * 40 + quad * 8);
        f32x4 a0 = MFMA(af, Uf[0], xa[0], 0, 0, 0);
        f32x4 a1 = MFMA(af, Uf[1], xa[1], 0, 0, 0);
        f32x4 a2 = MFMA(af, Uf[2], xa[2], 0, 0, 0);
        f32x4 a3 = MFMA(af, Uf[3], xa[3], 0, 0, 0);

        xa[0] = MFMA(x0, Wf[0][0], biasC[0], 0, 0, 0);
        xa[1] = MFMA(x0, Wf[1][0], biasC[1], 0, 0, 0);
        xa[2] = MFMA(x0, Wf[2][0], biasC[2], 0, 0, 0);
        xa[3] = MFMA(x0, Wf[3][0], biasC[3], 0, 0, 0);
        xa[0] = MFMA(x1, Wf[0][1], xa[0], 0, 0, 0);
        xa[1] = MFMA(x1, Wf[1][1], xa[1], 0, 0, 0);
        xa[2] = MFMA(x1, Wf[2][1], xa[2], 0, 0, 0);
        xa[3] = MFMA(x1, Wf[3][1], xa[3], 0, 0, 0);

        if (s + 4 < T) {
            const unsigned short* pn = hl + (size_t)(d ? (T - 5 - s) : (s + 4)) * 1024;
            x0 = *(const bf16x8*)(pn); x1 = *(const bf16x8*)(pn + 512);
        }

        // wave-uniform row select: wave sh owns sample quad*4+sh
        float z0, z1, z2, z3;
        if (sh == 0)      { z0 = a0[0]; z1 = a1[0]; z2 = a2[0]; z3 = a3[0]; }
        else if (sh == 1) { z0 = a0[1]; z1 = a1[1]; z2 = a2[1]; z3 = a3[1]; }
        else if (sh == 2) { z0 = a0[2]; z1 = a1[2]; z2 = a2[2]; z3 = a3[2]; }
        else              { z0 = a0[3]; z1 = a1[3]; z2 = a2[3]; z3 = a3[3]; }
        const float ig = sigmoidf_(z0), fg = sigmoidf_(z1);
        const float gg = tanhf_(z2),   og = sigmoidf_(z3);
        c = fg * c + ig * gg;
        hlast = og * tanhf_(c);
        hx[(s + 1) & 1][(quad * 4 + sh) * 40 + n15] = f2bf(hlast);
        lds_barrier();
    };

    #pragma unroll 1
    for (int s = 0; s < T; s += 2) {
        step(s, xaA, hA0, hA1);
        step(s + 1, xaB, hB0, hB1);
    }

    hfin[(size_t)(g * 16 + quad * 4 + sh) * 32 + d * 16 + n15] = hlast;
}

// =============================================================================
// K3: dense head. One thread per sample: [32] -> swish(W3) -> sigmoid(W4).
// =============================================================================
__global__ __launch_bounds__(256) void head(
    const float* __restrict__ hfin,
    const float* __restrict__ W3, const float* __restrict__ b3,
    const float* __restrict__ W4, const float* __restrict__ b4,
    float* __restrict__ out, const int ns)
{
    const int i = blockIdx.x * 256 + threadIdx.x;
    if (i >= ns) return;
    float h[32];
    #pragma unroll
    for (int k = 0; k < 8; ++k)
        *(float4*)(h + k * 4) = *(const float4*)(hfin + (size_t)i * 32 + k * 4);
    float y[8];
    #pragma unroll
    for (int u = 0; u < 8; ++u) {
        float a = b3[u];
        #pragma unroll
        for (int k = 0; k < 32; ++k) a += h[k] * W3[k * 8 + u];
        y[u] = a * sigmoidf_(a);
    }
    #pragma unroll
    for (int o = 0; o < 2; ++o) {
        float a = b4[o];
        #pragma unroll
        for (int u = 0; u < 8; ++u) a += y[u] * W4[u * 2 + o];
        out[(size_t)i * 2 + o] = sigmoidf_(a);
    }
}

extern "C" void kernel_launch(void* const* d_in, const int* in_sizes, int n_in,
                              void* d_out, int out_size, void* d_ws, size_t ws_size,
                              hipStream_t stream) {
    const float* x   = (const float*)d_in[0];
    const float* W1f = (const float*)d_in[1];
    const float* U1f = (const float*)d_in[2];
    const float* b1f = (const float*)d_in[3];
    const float* W1b = (const float*)d_in[4];
    const float* U1b = (const float*)d_in[5];
    const float* b1b = (const float*)d_in[6];
    const float* W2f = (const float*)d_in[7];
    const float* U2f = (const float*)d_in[8];
    const float* b2f = (const float*)d_in[9];
    const float* W2b = (const float*)d_in[10];
    const float* U2b = (const float*)d_in[11];
    const float* b2b = (const float*)d_in[12];
    const float* W3  = (const float*)d_in[13];
    const float* b3  = (const float*)d_in[14];
    const float* W4  = (const float*)d_in[15];
    const float* b4  = (const float*)d_in[16];
    float* out = (float*)d_out;

    const int B  = in_sizes[0] / (T * F);
    const int NG = B / 16;                       // sample groups

    // ws: xbf (256 KB/group) + h1 (256 KB/group); hfin (fp32, tiny) ALIASES
    // the xbf region — xbf is dead once lstm1 finishes; stream order is safe.
    const size_t perG = (size_t)T * 1024 * sizeof(unsigned short);  // 256 KB
    int chG = (int)(ws_size / (2 * perG));
    if (chG > NG) chG = NG;
    if (chG < 1) chG = 1;
    unsigned short* xbf = (unsigned short*)d_ws;
    unsigned short* h1  = xbf + (size_t)chG * T * 1024;

    for (int g0 = 0; g0 < NG; g0 += chG) {
        const int cg = (NG - g0 < chG) ? (NG - g0) : chG;
        const int nf4 = cg * 16 * T * 16;        // float4 count
        xcvt<<<nf4 / 256, 256, 0, stream>>>(x + (size_t)g0 * 16 * T * F, xbf);
        lstm1_fused<<<cg * 2, 256, 0, stream>>>(
            xbf, W1f, b1f, U1f, W1b, b1b, U1b, h1);
        lstm2_rec<<<cg * 2, 256, 0, stream>>>(
            h1, W2f, b2f, U2f, W2b, b2b, U2b, (float*)xbf);
        head<<<(cg * 16 + 255) / 256, 256, 0, stream>>>(
            (float*)xbf, W3, b3, W4, b4, out + (size_t)g0 * 16 * 2, cg * 16);
    }
}

// Round 5
// 364.813 us; speedup vs baseline: 1.3144x; 1.0135x over previous
//
#include <hip/hip_runtime.h>
#include <hip/hip_bf16.h>

#define T 128
#define F 64
#define H1 32
#define G1 128   // 4*H1
#define H2 16
#define G2 64    // 4*H2

typedef __attribute__((ext_vector_type(8))) short bf16x8;
typedef __attribute__((ext_vector_type(4))) float f32x4;

#define MFMA __builtin_amdgcn_mfma_f32_16x16x32_bf16

#define LOG2E   1.4426950408889634f
#define TWOLOG2E 2.8853900817779268f

// Raw v_exp_f32 (exp2). Gate pre-activations are pre-scaled by log2e (sigmoid
// gates) / 2*log2e (g gate) via the WEIGHTS, so no per-element multiply.
__device__ __forceinline__ float exp2_(float x) {
    float r; asm("v_exp_f32 %0, %1" : "=v"(r) : "v"(x)); return r;
}
__device__ __forceinline__ float exp2n_(float x) {   // exp2(-x), free modifier
    float r; asm("v_exp_f32 %0, -%1" : "=v"(r) : "v"(x)); return r;
}
// z' = log2e * z  ->  sigmoid(z)
__device__ __forceinline__ float sig2_(float zp) {
    return __builtin_amdgcn_rcpf(1.0f + exp2n_(zp));
}
// z' = 2*log2e * z  ->  tanh(z)
__device__ __forceinline__ float tanh2_(float zp) {
    return 1.0f - 2.0f * __builtin_amdgcn_rcpf(exp2_(zp) + 1.0f);
}
// plain-domain sigmoid for the head
__device__ __forceinline__ float sigmoidf_(float x) {
    return __builtin_amdgcn_rcpf(1.0f + exp2n_(x * LOG2E));
}
__device__ __forceinline__ unsigned short f2bf(float f) {
    union { float f; unsigned u; } c; c.f = f;
    unsigned r = c.u + 0x7FFF + ((c.u >> 16) & 1);   // RTNE
    return (unsigned short)(r >> 16);
}
// LDS-only barrier: waits DS ops, does NOT drain vmcnt.
__device__ __forceinline__ void lds_barrier() {
    asm volatile("s_waitcnt lgkmcnt(0)" ::: "memory");
    __builtin_amdgcn_s_barrier();
}

// =============================================================================
// K0: x fp32 -> bf16, A-fragment-packed, GATHER form: thread = one OUTPUT
// ushort4 -> stores perfectly coalesced (one block owns whole 2KB pages);
// loads are 128B-contiguous chunks per 8-lane group (full line use).
// slot(m, k) = (k>>5)*512 + (m + 16*((k&31)>>3))*8 + (k&7)
// =============================================================================
__global__ __launch_bounds__(256) void xcvt(
    const float* __restrict__ x,          // [B][T][64]
    unsigned short* __restrict__ xbf)
{
    const size_t i = (size_t)blockIdx.x * 256 + threadIdx.x;   // ushort4 index
    const int o = (int)(i & 255) * 4;          // short offset within page
    const size_t p = i >> 8;                   // page = g*T + t
    const int t = (int)(p & (T - 1));
    const size_t g = p >> 7;
    const int ks   = o >> 9;
    const int idx8 = (o & 511) >> 3;           // m + 16*q
    const int m = idx8 & 15, q = idx8 >> 4;
    const int j0 = o & 7;                      // 0 or 4
    const float4 v = *(const float4*)(
        x + ((g * 16 + m) * T + t) * 64 + ks * 32 + q * 8 + j0);
    ushort4 u;
    u.x = f2bf(v.x); u.y = f2bf(v.y); u.z = f2bf(v.z); u.w = f2bf(v.w);
    *(ushort4*)(xbf + i * 4) = u;
}

// =============================================================================
// K1: layer-1 recurrence (r1-proven shape). Block = (g, d), 4 waves
// (gh = gate-half, sh = sample-half); 2 blocks/CU, 2 waves/SIMD. xa built one
// step ahead; post-barrier path is ds_read -> 1 U-MFMA -> activation.
// Weights pre-scaled to exp2 domain (see sig2_/tanh2_).
// =============================================================================
__global__ __launch_bounds__(256, 2) void lstm1_fused(
    const unsigned short* __restrict__ xbf,
    const float* __restrict__ W1f, const float* __restrict__ b1f, const float* __restrict__ U1f,
    const float* __restrict__ W1b, const float* __restrict__ b1b, const float* __restrict__ U1b,
    unsigned short* __restrict__ h1)     // packed per (g,t), 1024 shorts
{
    __shared__ unsigned short hb[2][16 * 40];
    const int tid  = threadIdx.x;
    const int lane = tid & 63;
    const int wv   = __builtin_amdgcn_readfirstlane(tid >> 6);
    const int gh   = wv & 1;
    const int sh   = wv >> 1;            // 0..1
    const int n15  = lane & 15, quad = lane >> 4;
    const int d    = blockIdx.x & 1, g = blockIdx.x >> 1;

    const float* W  = d ? W1b : W1f;
    const float* U  = d ? U1b : U1f;
    const float* bs = d ? b1b : b1f;

    // frag q = 2*i + gh covers gate cols q*16+n15; gate index == i
    bf16x8 Wf[4][2], Uf[4];
    f32x4 biasC[4];
    #pragma unroll
    for (int i = 0; i < 4; ++i) {
        const float sc = (i == 2) ? TWOLOG2E : LOG2E;
        const int col = (2 * i + gh) * 16 + n15;
        biasC[i] = (f32x4)(bs[col] * sc);
        #pragma unroll
        for (int ks = 0; ks < 2; ++ks) {
            bf16x8 f;
            #pragma unroll
            for (int j = 0; j < 8; ++j)
                f[j] = (short)f2bf(W[(ks * 32 + quad * 8 + j) * G1 + col] * sc);
            Wf[i][ks] = f;
        }
        bf16x8 u;
        #pragma unroll
        for (int j = 0; j < 8; ++j)
            u[j] = (short)f2bf(U[(quad * 8 + j) * G1 + col] * sc);
        Uf[i] = u;
    }

    // zero h(-1) buffer + pads (1280 shorts total)
    #pragma unroll
    for (int i = 0; i < 5; ++i) ((unsigned short*)hb)[tid + i * 256] = 0;

    float c0 = 0.0f, c1 = 0.0f;
    const unsigned short* xb = xbf + (size_t)g * T * 1024 + lane * 8;
    unsigned short* h1b0 = h1 + (size_t)g * T * 1024
        + d * 512 + ((quad * 4 + 2 * sh) + 16 * (gh * 2 + (n15 >> 3))) * 8 + (n15 & 7);
    unsigned short* h1b1 = h1b0 + 8;

    // prologue: xa for steps 0/1; prefetch x for steps 2/3
    f32x4 xaA[4], xaB[4];
    bf16x8 xA0, xA1, xB0, xB1;
    {
        const unsigned short* p0 = xb + (size_t)(d ? (T - 1) : 0) * 1024;
        bf16x8 t0 = *(const bf16x8*)(p0), t1 = *(const bf16x8*)(p0 + 512);
        #pragma unroll
        for (int i = 0; i < 4; ++i) {
            xaA[i] = MFMA(t0, Wf[i][0], biasC[i], 0, 0, 0);
            xaA[i] = MFMA(t1, Wf[i][1], xaA[i], 0, 0, 0);
        }
        const unsigned short* p1 = xb + (size_t)(d ? (T - 2) : 1) * 1024;
        t0 = *(const bf16x8*)(p1); t1 = *(const bf16x8*)(p1 + 512);
        #pragma unroll
        for (int i = 0; i < 4; ++i) {
            xaB[i] = MFMA(t0, Wf[i][0], biasC[i], 0, 0, 0);
            xaB[i] = MFMA(t1, Wf[i][1], xaB[i], 0, 0, 0);
        }
        const unsigned short* p2 = xb + (size_t)(d ? (T - 3) : 2) * 1024;
        xA0 = *(const bf16x8*)(p2); xA1 = *(const bf16x8*)(p2 + 512);
        const unsigned short* p3 = xb + (size_t)(d ? (T - 4) : 3) * 1024;
        xB0 = *(const bf16x8*)(p3); xB1 = *(const bf16x8*)(p3 + 512);
    }
    lds_barrier();

    auto step = [&](int s, f32x4* xa, bf16x8& x0, bf16x8& x1) {
        const bf16x8 af = *(const bf16x8*)(hb[s & 1] + n15 * 40 + quad * 8);
        f32x4 a0 = MFMA(af, Uf[0], xa[0], 0, 0, 0);
        f32x4 a1 = MFMA(af, Uf[1], xa[1], 0, 0, 0);
        f32x4 a2 = MFMA(af, Uf[2], xa[2], 0, 0, 0);
        f32x4 a3 = MFMA(af, Uf[3], xa[3], 0, 0, 0);

        xa[0] = MFMA(x0, Wf[0][0], biasC[0], 0, 0, 0);
        xa[1] = MFMA(x0, Wf[1][0], biasC[1], 0, 0, 0);
        xa[2] = MFMA(x0, Wf[2][0], biasC[2], 0, 0, 0);
        xa[3] = MFMA(x0, Wf[3][0], biasC[3], 0, 0, 0);
        xa[0] = MFMA(x1, Wf[0][1], xa[0], 0, 0, 0);
        xa[1] = MFMA(x1, Wf[1][1], xa[1], 0, 0, 0);
        xa[2] = MFMA(x1, Wf[2][1], xa[2], 0, 0, 0);
        xa[3] = MFMA(x1, Wf[3][1], xa[3], 0, 0, 0);

        if (s + 4 < T) {
            const unsigned short* pn = xb + (size_t)(d ? (T - 5 - s) : (s + 4)) * 1024;
            x0 = *(const bf16x8*)(pn); x1 = *(const bf16x8*)(pn + 512);
        }

        const int t = d ? (T - 1 - s) : s;
        float zi0, zi1, zf0, zf1, zg0, zg1, zo0, zo1;
        if (sh == 0) {
            zi0 = a0[0]; zi1 = a0[1]; zf0 = a1[0]; zf1 = a1[1];
            zg0 = a2[0]; zg1 = a2[1]; zo0 = a3[0]; zo1 = a3[1];
        } else {
            zi0 = a0[2]; zi1 = a0[3]; zf0 = a1[2]; zf1 = a1[3];
            zg0 = a2[2]; zg1 = a2[3]; zo0 = a3[2]; zo1 = a3[3];
        }
        {   // sample quad*4 + 2*sh
            const float ig = sig2_(zi0), fg = sig2_(zf0);
            const float gg = tanh2_(zg0), og = sig2_(zo0);
            c0 = fg * c0 + ig * gg;
            const float h = og * tanh2_(c0 * TWOLOG2E);
            const unsigned short us = f2bf(h);
            hb[(s + 1) & 1][(quad * 4 + 2 * sh) * 40 + gh * 16 + n15] = us;
            h1b0[(size_t)t * 1024] = us;
        }
        {   // sample quad*4 + 2*sh + 1
            const float ig = sig2_(zi1), fg = sig2_(zf1);
            const float gg = tanh2_(zg1), og = sig2_(zo1);
            c1 = fg * c1 + ig * gg;
            const float h = og * tanh2_(c1 * TWOLOG2E);
            const unsigned short us = f2bf(h);
            hb[(s + 1) & 1][(quad * 4 + 2 * sh + 1) * 40 + gh * 16 + n15] = us;
            h1b1[(size_t)t * 1024] = us;
        }
        lds_barrier();
    };

    #pragma unroll 1
    for (int s = 0; s < T; s += 2) {
        step(s, xaA, xA0, xA1);
        step(s + 1, xaB, xB0, xB1);
    }
}

// =============================================================================
// K2: layer-2 recurrence, r1-lstm1 shape: block = (g, d), 512 blocks x 4
// waves (sh = 0..3) -> 2 blocks/CU. MFMAs duplicated across sh; activation
// 1 elem/lane. U2 zero-padded to K=32 via zeroed LDS cols 16..39.
// =============================================================================
__global__ __launch_bounds__(256, 2) void lstm2_rec(
    const unsigned short* __restrict__ h1,
    const float* __restrict__ W2f, const float* __restrict__ b2f, const float* __restrict__ U2f,
    const float* __restrict__ W2b, const float* __restrict__ b2b, const float* __restrict__ U2b,
    float* __restrict__ hfin)            // [ns][32]
{
    __shared__ unsigned short hx[2][16 * 40];   // cols 16..39 stay zero
    const int tid  = threadIdx.x;
    const int lane = tid & 63;
    const int sh   = __builtin_amdgcn_readfirstlane(tid >> 6);   // 0..3
    const int n15  = lane & 15, quad = lane >> 4;
    const int d    = blockIdx.x & 1, g = blockIdx.x >> 1;

    const float* W  = d ? W2b : W2f;
    const float* U  = d ? U2b : U2f;
    const float* bs = d ? b2b : b2f;

    bf16x8 Wf[4][2], Uf[4];
    f32x4 biasC[4];
    #pragma unroll
    for (int i = 0; i < 4; ++i) {
        const float sc = (i == 2) ? TWOLOG2E : LOG2E;
        const int col = i * 16 + n15;        // gate i, unit n15
        biasC[i] = (f32x4)(bs[col] * sc);
        #pragma unroll
        for (int ks = 0; ks < 2; ++ks) {
            bf16x8 f;
            #pragma unroll
            for (int j = 0; j < 8; ++j)
                f[j] = (short)f2bf(W[(ks * 32 + quad * 8 + j) * G2 + col] * sc);
            Wf[i][ks] = f;
        }
        bf16x8 uu;
        #pragma unroll
        for (int j = 0; j < 8; ++j) {
            const int k = quad * 8 + j;
            uu[j] = (k < H2) ? (short)f2bf(U[k * G2 + col] * sc) : (short)0;
        }
        Uf[i] = uu;
    }

    // zero both buffers: 1280 shorts / 256 threads = 5 each
    #pragma unroll
    for (int i = 0; i < 5; ++i) ((unsigned short*)hx)[tid + i * 256] = 0;

    float c = 0.0f, hlast = 0.0f;
    const unsigned short* hl = h1 + (size_t)g * T * 1024 + lane * 8;

    f32x4 xaA[4], xaB[4];
    bf16x8 hA0, hA1, hB0, hB1;
    {
        const unsigned short* p0 = hl + (size_t)(d ? (T - 1) : 0) * 1024;
        bf16x8 t0 = *(const bf16x8*)(p0), t1 = *(const bf16x8*)(p0 + 512);
        #pragma unroll
        for (int i = 0; i < 4; ++i) {
            xaA[i] = MFMA(t0, Wf[i][0], biasC[i], 0, 0, 0);
            xaA[i] = MFMA(t1, Wf[i][1], xaA[i], 0, 0, 0);
        }
        const unsigned short* p1 = hl + (size_t)(d ? (T - 2) : 1) * 1024;
        t0 = *(const bf16x8*)(p1); t1 = *(const bf16x8*)(p1 + 512);
        #pragma unroll
        for (int i = 0; i < 4; ++i) {
            xaB[i] = MFMA(t0, Wf[i][0], biasC[i], 0, 0, 0);
            xaB[i] = MFMA(t1, Wf[i][1], xaB[i], 0, 0, 0);
        }
        const unsigned short* p2 = hl + (size_t)(d ? (T - 3) : 2) * 1024;
        hA0 = *(const bf16x8*)(p2); hA1 = *(const bf16x8*)(p2 + 512);
        const unsigned short* p3 = hl + (size_t)(d ? (T - 4) : 3) * 1024;
        hB0 = *(const bf16x8*)(p3); hB1 = *(const bf16x8*)(p3 + 512);
    }
    lds_barrier();

    auto step = [&](int s, f32x4* xa, bf16x8& x0, bf16x8& x1) {
        const bf16x8 af = *(const bf16x8*)(hx[s & 1] + n15 * 40 + quad * 8);
        f32x4 a0 = MFMA(af, Uf[0], xa[0], 0, 0, 0);
        f32x4 a1 = MFMA(af, Uf[1], xa[1], 0, 0, 0);
        f32x4 a2 = MFMA(af, Uf[2], xa[2], 0, 0, 0);
        f32x4 a3 = MFMA(af, Uf[3], xa[3], 0, 0, 0);

        xa[0] = MFMA(x0, Wf[0][0], biasC[0], 0, 0, 0);
        xa[1] = MFMA(x0, Wf[1][0], biasC[1], 0, 0, 0);
        xa[2] = MFMA(x0, Wf[2][0], biasC[2], 0, 0, 0);
        xa[3] = MFMA(x0, Wf[3][0], biasC[3], 0, 0, 0);
        xa[0] = MFMA(x1, Wf[0][1], xa[0], 0, 0, 0);
        xa[1] = MFMA(x1, Wf[1][1], xa[1], 0, 0, 0);
        xa[2] = MFMA(x1, Wf[2][1], xa[2], 0, 0, 0);
        xa[3] = MFMA(x1, Wf[3][1], xa[3], 0, 0, 0);

        if (s + 4 < T) {
            const unsigned short* pn = hl + (size_t)(d ? (T - 5 - s) : (s + 4)) * 1024;
            x0 = *(const bf16x8*)(pn); x1 = *(const bf16x8*)(pn + 512);
        }

        // wave-uniform row select: wave sh owns sample quad*4+sh
        float z0, z1, z2, z3;
        if (sh == 0)      { z0 = a0[0]; z1 = a1[0]; z2 = a2[0]; z3 = a3[0]; }
        else if (sh == 1) { z0 = a0[1]; z1 = a1[1]; z2 = a2[1]; z3 = a3[1]; }
        else if (sh == 2) { z0 = a0[2]; z1 = a1[2]; z2 = a2[2]; z3 = a3[2]; }
        else              { z0 = a0[3]; z1 = a1[3]; z2 = a2[3]; z3 = a3[3]; }
        const float ig = sig2_(z0), fg = sig2_(z1);
        const float gg = tanh2_(z2), og = sig2_(z3);
        c = fg * c + ig * gg;
        hlast = og * tanh2_(c * TWOLOG2E);
        hx[(s + 1) & 1][(quad * 4 + sh) * 40 + n15] = f2bf(hlast);
        lds_barrier();
    };

    #pragma unroll 1
    for (int s = 0; s < T; s += 2) {
        step(s, xaA, hA0, hA1);
        step(s + 1, xaB, hB0, hB1);
    }

    hfin[(size_t)(g * 16 + quad * 4 + sh) * 32 + d * 16 + n15] = hlast;
}

// =============================================================================
// K3: dense head. One thread per sample: [32] -> swish(W3) -> sigmoid(W4).
// =============================================================================
__global__ __launch_bounds__(256) void head(
    const float* __restrict__ hfin,
    const float* __restrict__ W3, const float* __restrict__ b3,
    const float* __restrict__ W4, const float* __restrict__ b4,
    float* __restrict__ out, const int ns)
{
    const int i = blockIdx.x * 256 + threadIdx.x;
    if (i >= ns) return;
    float h[32];
    #pragma unroll
    for (int k = 0; k < 8; ++k)
        *(float4*)(h + k * 4) = *(const float4*)(hfin + (size_t)i * 32 + k * 4);
    float y[8];
    #pragma unroll
    for (int u = 0; u < 8; ++u) {
        float a = b3[u];
        #pragma unroll
        for (int k = 0; k < 32; ++k) a += h[k] * W3[k * 8 + u];
        y[u] = a * sigmoidf_(a);
    }
    #pragma unroll
    for (int o = 0; o < 2; ++o) {
        float a = b4[o];
        #pragma unroll
        for (int u = 0; u < 8; ++u) a += y[u] * W4[u * 2 + o];
        out[(size_t)i * 2 + o] = sigmoidf_(a);
    }
}

extern "C" void kernel_launch(void* const* d_in, const int* in_sizes, int n_in,
                              void* d_out, int out_size, void* d_ws, size_t ws_size,
                              hipStream_t stream) {
    const float* x   = (const float*)d_in[0];
    const float* W1f = (const float*)d_in[1];
    const float* U1f = (const float*)d_in[2];
    const float* b1f = (const float*)d_in[3];
    const float* W1b = (const float*)d_in[4];
    const float* U1b = (const float*)d_in[5];
    const float* b1b = (const float*)d_in[6];
    const float* W2f = (const float*)d_in[7];
    const float* U2f = (const float*)d_in[8];
    const float* b2f = (const float*)d_in[9];
    const float* W2b = (const float*)d_in[10];
    const float* U2b = (const float*)d_in[11];
    const float* b2b = (const float*)d_in[12];
    const float* W3  = (const float*)d_in[13];
    const float* b3  = (const float*)d_in[14];
    const float* W4  = (const float*)d_in[15];
    const float* b4  = (const float*)d_in[16];
    float* out = (float*)d_out;

    const int B  = in_sizes[0] / (T * F);
    const int NG = B / 16;                       // sample groups

    // ws: xbf (256 KB/group) + h1 (256 KB/group); hfin (fp32, tiny) ALIASES
    // the xbf region — xbf is dead once lstm1 finishes; stream order is safe.
    const size_t perG = (size_t)T * 1024 * sizeof(unsigned short);  // 256 KB
    int chG = (int)(ws_size / (2 * perG));
    if (chG > NG) chG = NG;
    if (chG < 1) chG = 1;
    unsigned short* xbf = (unsigned short*)d_ws;
    unsigned short* h1  = xbf + (size_t)chG * T * 1024;

    for (int g0 = 0; g0 < NG; g0 += chG) {
        const int cg = (NG - g0 < chG) ? (NG - g0) : chG;
        xcvt<<<cg * T, 256, 0, stream>>>(x + (size_t)g0 * 16 * T * F, xbf);
        lstm1_fused<<<cg * 2, 256, 0, stream>>>(
            xbf, W1f, b1f, U1f, W1b, b1b, U1b, h1);
        lstm2_rec<<<cg * 2, 256, 0, stream>>>(
            h1, W2f, b2f, U2f, W2b, b2b, U2b, (float*)xbf);
        head<<<(cg * 16 + 255) / 256, 256, 0, stream>>>(
            (float*)xbf, W3, b3, W4, b4, out + (size_t)g0 * 16 * 2, cg * 16);
    }
}